// Round 7
// baseline (584.967 us; speedup 1.0000x reference)
//
#include <hip/hip_runtime.h>
#include <math.h>

// Problem constants
#define NL 2
#define NDIR 4
#define DD 256     // D (channels)
#define DIN 512    // DI (inner)
#define NS 16      // N (state)
#define BB 8       // batch
#define LL 256     // L = H*W
#define BL 2048    // B*L

typedef short s16x8 __attribute__((ext_vector_type(8)));
typedef short s16x4 __attribute__((ext_vector_type(4)));
typedef float f32x4 __attribute__((ext_vector_type(4)));

// fast-math device helpers (tolerance 4.56e-2 >> 2-ulp native error)
__device__ __forceinline__ float fsilu(float x){ return __fdividef(x, 1.f + __expf(-x)); }
__device__ __forceinline__ float fsigmoid(float x){ return __fdividef(1.f, 1.f + __expf(-x)); }
__device__ __forceinline__ float fsoftplus(float x){ return fmaxf(x, 0.f) + __logf(1.f + __expf(-fabsf(x))); }
__device__ __forceinline__ float geluf(float x){ return 0.5f * x * (1.f + erff(x * 0.70710678118654752f)); }
__device__ __forceinline__ short cvtbf(float f){
  unsigned u = __float_as_uint(f);
  u += 0x7FFF + ((u >> 16) & 1);
  return (short)(u >> 16);
}
__device__ __forceinline__ float bf2f(short s){
  return __uint_as_float(((unsigned)(unsigned short)s) << 16);
}
__device__ __forceinline__ int perml(int l, int d){
  int h = l >> 4, w = l & 15;
  if (d & 1) w = 15 - w;
  if (d & 2) h = 15 - h;
  return (h << 4) | w;
}

// feat (B,C,H,W) -> x (B,L,C)
__global__ __launch_bounds__(256) void k_transpose(const float* __restrict__ feat, float* __restrict__ x){
  int idx = blockIdx.x * 256 + threadIdx.x;
  int c = idx & 255, l = (idx >> 8) & 255, b = idx >> 16;
  x[idx] = feat[((b * DD + c) * 16 + (l >> 4)) * 16 + (l & 15)];
}

__global__ __launch_bounds__(256) void k_gate(const float* __restrict__ alt_embed, const int* __restrict__ alt_idx,
                      const float* __restrict__ gate_w, const float* __restrict__ gate_b,
                      float* __restrict__ gate){
  int idx = blockIdx.x * 256 + threadIdx.x;
  int c = idx & 255, b = (idx >> 8) & 7, li = idx >> 11;
  const float* ae = alt_embed + alt_idx[b] * 32;
  const float* gw = gate_w + ((long)li * DD + c) * 32;
  float acc = gate_b[li * DD + c];
  #pragma unroll
  for (int j = 0; j < 32; j++) acc += ae[j] * gw[j];
  gate[idx] = fsigmoid(acc);
}

// Aexp = -exp(A_log), whole tensor (65536)
__global__ __launch_bounds__(256) void k_aexp(const float* __restrict__ A_log, float* __restrict__ Aexp){
  int idx = blockIdx.x * 256 + threadIdx.x;
  Aexp[idx] = -expf(A_log[idx]);
}

// Convert all 5 GEMM weight tensors fp32->bf16 into one pool
#define WOFF_IN   0L
#define WOFF_XP   2097152L
#define WOFF_OUT  2293760L
#define WOFF_F1   3342336L
#define WOFF_F2   4390912L
#define WTOT      4653056L
__global__ __launch_bounds__(256) void k_wcvt(const float* __restrict__ s0, const float* __restrict__ s1,
      const float* __restrict__ s2, const float* __restrict__ s3, const float* __restrict__ s4,
      short* __restrict__ dst){
  long e = ((long)blockIdx.x * 256 + threadIdx.x) * 4;
  const float* src; long off;
  if      (e < WOFF_XP) { src = s0; off = e; }
  else if (e < WOFF_OUT){ src = s1; off = e - WOFF_XP; }
  else if (e < WOFF_F1) { src = s2; off = e - WOFF_OUT; }
  else if (e < WOFF_F2) { src = s3; off = e - WOFF_F1; }
  else                  { src = s4; off = e - WOFF_F2; }
  f32x4 v = *(const f32x4*)(src + off);
  s16x4 o = { cvtbf(v[0]), cvtbf(v[1]), cvtbf(v[2]), cvtbf(v[3]) };
  *(s16x4*)(dst + e) = o;
}

// MFMA bf16 GEMM: C[m,n] = act(sum_k A[m,k]*W[n,k] + bias[n])
// W: bf16 (N,K). ALAY 0: A bf16 row-major. ALAY 1: A fp32 gathered from x (B,L,C) via perml(dir=blockIdx.z).
// ACT: 0 none, 1 gelu, 2 split-silu-bf16 (n<512 raw bf16->Cv, n>=512 silu bf16->Cv2; both row stride 512)
template<int WM, int WN, int ACT, bool BIAS, bool OBF, int ALAY>
__global__ __launch_bounds__(256) void k_mgemm(const void* __restrict__ Av, const short* __restrict__ W,
        const float* __restrict__ bias, void* __restrict__ Cv, void* __restrict__ Cv2,
        int M, int N, int K, long aB, long wB, long cB){
  constexpr int TM = WM * 64, TN = WN * 64;
  __shared__ short As[TM][40];
  __shared__ short Ws[TN][40];
  int m0 = blockIdx.x * TM, n0 = blockIdx.y * TN, d = blockIdx.z;
  int t = threadIdx.x;
  int wave = t >> 6, lane = t & 63;
  int wr = wave / WN, wc = wave % WN;
  int lq = lane >> 4, lr = lane & 15;
  const short* Wd = W + (long)d * wB;
  f32x4 acc[4][4];
  #pragma unroll
  for (int i = 0; i < 4; i++)
    #pragma unroll
    for (int j = 0; j < 4; j++) acc[i][j] = (f32x4){0.f, 0.f, 0.f, 0.f};

  for (int kb = 0; kb < K; kb += 32){
    if (ALAY == 0){
      const short* Ad = (const short*)Av + (long)d * aB;
      #pragma unroll
      for (int r = 0; r < WM; r++){
        int e = r * 256 + t;
        int row = e >> 2, c8 = e & 3;
        s16x8 v = *(const s16x8*)(Ad + (long)(m0 + row) * K + kb + c8 * 8);
        *(s16x8*)&As[row][c8 * 8] = v;
      }
    } else {
      const float* Aq = (const float*)Av;
      #pragma unroll
      for (int r = 0; r < 2 * WM; r++){
        int e = r * 256 + t;
        int row = e >> 3, c4 = e & 7;
        int m = m0 + row;
        const float* src = Aq + ((long)((m >> 8) << 8) + perml(m & 255, d)) * 256 + kb + c4 * 4;
        f32x4 v = *(const f32x4*)src;
        s16x4 sv = { cvtbf(v[0]), cvtbf(v[1]), cvtbf(v[2]), cvtbf(v[3]) };
        *(s16x4*)&As[row][c4 * 4] = sv;
      }
    }
    #pragma unroll
    for (int r = 0; r < WN; r++){
      int e = r * 256 + t;
      int row = e >> 2, c8 = e & 3;
      int n = n0 + row;
      s16x8 v = (s16x8){0,0,0,0,0,0,0,0};
      if (n < N) v = *(const s16x8*)(Wd + (long)n * K + kb + c8 * 8);
      *(s16x8*)&Ws[row][c8 * 8] = v;
    }
    __syncthreads();
    s16x8 af[4], wf[4];
    #pragma unroll
    for (int mi = 0; mi < 4; mi++) af[mi] = *(const s16x8*)&As[wr * 64 + mi * 16 + lr][lq * 8];
    #pragma unroll
    for (int ni = 0; ni < 4; ni++) wf[ni] = *(const s16x8*)&Ws[wc * 64 + ni * 16 + lr][lq * 8];
    #pragma unroll
    for (int mi = 0; mi < 4; mi++)
      #pragma unroll
      for (int ni = 0; ni < 4; ni++)
        acc[mi][ni] = __builtin_amdgcn_mfma_f32_16x16x32_bf16(af[mi], wf[ni], acc[mi][ni], 0, 0, 0);
    __syncthreads();
  }

  #pragma unroll
  for (int mi = 0; mi < 4; mi++){
    #pragma unroll
    for (int ni = 0; ni < 4; ni++){
      int n = n0 + wc * 64 + ni * 16 + lr;
      if (n < N){
        float bv = BIAS ? bias[n] : 0.f;
        #pragma unroll
        for (int r = 0; r < 4; r++){
          int m = m0 + wr * 64 + mi * 16 + lq * 4 + r;
          float v = acc[mi][ni][r] + bv;
          if (ACT == 1) v = geluf(v);
          if (ACT == 2){
            if (n < DIN) ((short*)Cv )[(long)d * cB + (long)m * DIN + n]         = cvtbf(v);
            else         ((short*)Cv2)[(long)d * cB + (long)m * DIN + (n - DIN)] = cvtbf(fsilu(v));
          } else {
            if (OBF) ((short*)Cv)[(long)d * cB + (long)m * N + n] = cvtbf(v);
            else     ((float*)Cv)[(long)d * cB + (long)m * N + n] = v;
          }
        }
      }
    }
  }
}

// causal depthwise conv (K=4) + silu on bf16 xinb[db,l,512]; writes bf16 xcbf[db,l,i]
__global__ __launch_bounds__(256) void k_conv(const short* __restrict__ xinb, const float* __restrict__ cw,
                      const float* __restrict__ cb, short* __restrict__ xcbf){
  int it = blockIdx.x * 64, lc = blockIdx.y * 128, db = blockIdx.z;
  int d = db >> 3;
  int t = threadIdx.x;
  __shared__ float xs[64][131];
  const short* src = xinb + (long)db * LL * DIN;
  for (int e = t; e < 131 * 64; e += 256){
    int il = e & 63, lh = e >> 6;
    int gl = lc - 3 + lh;
    xs[il][lh] = (gl >= 0) ? bf2f(src[(long)gl * DIN + it + il]) : 0.f;
  }
  __syncthreads();
  const float* cwp = cw + ((long)d * DIN + it) * 4;
  const float* cbp = cb + (long)d * DIN + it;
  for (int e = t; e < 64 * 128; e += 256){
    int il = e & 63, lh = e >> 6;
    float acc = cbp[il];
    #pragma unroll
    for (int k = 0; k < 4; k++) acc += xs[il][lh + k] * cwp[il * 4 + k];
    xcbf[((long)db * LL + lc + lh) * DIN + it + il] = cvtbf(fsilu(acc));
  }
}

// windowed scan (K=8) — chunked, LDS-free, native exp, dt fused.
// Thread = (i, s-half) for one 8-l chunk. dt via half-dot + shfl_xor + softplus.
__global__ __launch_bounds__(512) void k_scan(
    const short* __restrict__ xcbf, const short* __restrict__ zbf,
    const float* __restrict__ x_dbl, const float* __restrict__ Aexp,
    const float* __restrict__ dt_w, const float* __restrict__ dt_b,
    const float* __restrict__ Dp, short* __restrict__ ybf){
  int bx = blockIdx.x;
  int itile = bx & 1, chunk = bx >> 1;
  int b = blockIdx.y, d = blockIdx.z;
  int db = d * BB + b;
  int tid = threadIdx.x;
  int half = tid & 1;
  int i = itile * 256 + (tid >> 1);
  int bs = chunk * 8;
  const float* alp = Aexp + ((long)(d * DIN + i)) * 16 + half * 8;
  float A[8], W8[8];
  *(f32x4*)&A[0] = *(const f32x4*)(alp);
  *(f32x4*)&A[4] = *(const f32x4*)(alp + 4);
  const float* wdt = dt_w + ((long)(d * DIN + i)) * 16 + half * 8;
  *(f32x4*)&W8[0] = *(const f32x4*)(wdt);
  *(f32x4*)&W8[4] = *(const f32x4*)(wdt + 4);
  float bdt = dt_b[d * DIN + i];
  float Di = Dp[d * DIN + i];
  const float* xdb = x_dbl + (long)db * LL * 48;
  long pix = (long)db * LL * DIN + i;   // + l*DIN

  float T[8], R[7][8], P[8];
  #pragma unroll
  for (int s = 0; s < 8; s++){ T[s] = 0.f; P[s] = 1.f; }
  if (bs > 0){
    #pragma unroll
    for (int m = 1; m <= 7; m++){
      int j = bs - m;
      const float* rp = xdb + j * 48 + half * 8;
      f32x4 d0 = *(const f32x4*)rp, d1 = *(const f32x4*)(rp + 4);
      f32x4 b0 = *(const f32x4*)(rp + 16), b1 = *(const f32x4*)(rp + 20);
      float part = 0.f;
      #pragma unroll
      for (int s = 0; s < 8; s++) part += ((s < 4) ? d0[s] : d1[s - 4]) * W8[s];
      float dt = fsoftplus(part + __shfl_xor(part, 1) + bdt);
      float xc = bf2f(xcbf[pix + (long)j * DIN]);
      float dx = dt * xc;
      #pragma unroll
      for (int s = 0; s < 8; s++){
        float Bv = (s < 4) ? b0[s] : b1[s - 4];
        float E = __expf(A[s] * dt);
        float Rv = P[s] * (dx * Bv);
        R[m - 1][s] = Rv;
        T[s] += Rv;
        P[s] *= E;
      }
    }
  } else {
    #pragma unroll
    for (int m = 0; m < 7; m++)
      #pragma unroll
      for (int s = 0; s < 8; s++) R[m][s] = 0.f;
  }
  float h[8], Q[8];
  #pragma unroll
  for (int s = 0; s < 8; s++){ h[s] = 0.f; Q[s] = 1.f; }
  #pragma unroll
  for (int r = 0; r < 8; r++){
    int l = bs + r;
    const float* rp = xdb + l * 48 + half * 8;
    f32x4 d0 = *(const f32x4*)rp, d1 = *(const f32x4*)(rp + 4);
    f32x4 b0 = *(const f32x4*)(rp + 16), b1 = *(const f32x4*)(rp + 20);
    f32x4 c0 = *(const f32x4*)(rp + 32), c1 = *(const f32x4*)(rp + 36);
    float part = 0.f;
    #pragma unroll
    for (int s = 0; s < 8; s++) part += ((s < 4) ? d0[s] : d1[s - 4]) * W8[s];
    float dt = fsoftplus(part + __shfl_xor(part, 1) + bdt);
    float xc = bf2f(xcbf[pix + (long)l * DIN]);
    float z  = bf2f(zbf [pix + (long)l * DIN]);
    float dx = dt * xc;
    float y = 0.f;
    #pragma unroll
    for (int s = 0; s < 8; s++){
      float Bv = (s < 4) ? b0[s] : b1[s - 4];
      float Cv = (s < 4) ? c0[s] : c1[s - 4];
      float E = __expf(A[s] * dt);
      h[s] = E * h[s] + dx * Bv;
      Q[s] *= E;
      y += Cv * (h[s] + Q[s] * T[s]);
    }
    y += __shfl_xor(y, 1);
    if (half == 0){
      float outv = (y + Di * xc) * z;
      ybf[pix + (long)l * DIN] = cvtbf(outv);
    }
    if (r < 7){
      #pragma unroll
      for (int s = 0; s < 8; s++) T[s] -= R[6 - r][s];
    }
  }
}

// LN over C of (out_pre + residual from x via perml), write unflipped bf16 comb[b,t,d*256+c]
__global__ __launch_bounds__(256) void k_ln1(const float* __restrict__ out_pre, const float* __restrict__ x,
        const float* __restrict__ ng, const float* __restrict__ nb, short* __restrict__ comb_bf){
  int l = blockIdx.x, b = blockIdx.y, d = blockIdx.z, c = threadIdx.x;
  long row = ((long)(d * BB + b) * LL + l) * DD;
  int pl = perml(l, d);
  float v = out_pre[row + c] + x[((long)(b * LL) + pl) * DD + c];
  float s = v, q = v * v;
  #pragma unroll
  for (int off = 32; off; off >>= 1){ s += __shfl_down(s, off); q += __shfl_down(q, off); }
  __shared__ float ps[4], pq[4], mv[2];
  int wid = c >> 6;
  if ((c & 63) == 0){ ps[wid] = s; pq[wid] = q; }
  __syncthreads();
  if (c == 0){
    float ts = ps[0] + ps[1] + ps[2] + ps[3];
    float tq = pq[0] + pq[1] + pq[2] + pq[3];
    float m = ts / 256.f;
    mv[0] = m; mv[1] = rsqrtf(tq / 256.f - m * m + 1e-5f);
  }
  __syncthreads();
  float o = (v - mv[0]) * mv[1] * ng[d * DD + c] + nb[d * DD + c];
  comb_bf[((long)b * LL + pl) * 1024 + d * DD + c] = cvtbf(o);
}

// LN over C + gate multiply
__global__ __launch_bounds__(256) void k_ln2(const float* __restrict__ h2, const float* __restrict__ lg,
        const float* __restrict__ lb, const float* __restrict__ gate, float* __restrict__ dst){
  int l = blockIdx.x, b = blockIdx.y, c = threadIdx.x;
  long row = ((long)b * LL + l) * DD;
  float v = h2[row + c];
  float s = v, q = v * v;
  #pragma unroll
  for (int off = 32; off; off >>= 1){ s += __shfl_down(s, off); q += __shfl_down(q, off); }
  __shared__ float ps[4], pq[4], mv[2];
  int wid = c >> 6;
  if ((c & 63) == 0){ ps[wid] = s; pq[wid] = q; }
  __syncthreads();
  if (c == 0){
    float ts = ps[0] + ps[1] + ps[2] + ps[3];
    float tq = pq[0] + pq[1] + pq[2] + pq[3];
    float m = ts / 256.f;
    mv[0] = m; mv[1] = rsqrtf(tq / 256.f - m * m + 1e-5f);
  }
  __syncthreads();
  float o = (v - mv[0]) * mv[1] * lg[c] + lb[c];
  dst[row + c] = o * gate[b * DD + c];
}

extern "C" void kernel_launch(void* const* d_in, const int* in_sizes, int n_in,
                              void* d_out, int out_size, void* d_ws, size_t ws_size,
                              hipStream_t stream){
  const float* feat     = (const float*)d_in[0];
  const int*   alt_idx  = (const int*)d_in[1];
  const float* in_w     = (const float*)d_in[2];
  const float* dt_w     = (const float*)d_in[3];
  const float* dt_b     = (const float*)d_in[4];
  const float* A_log    = (const float*)d_in[5];
  const float* Dp       = (const float*)d_in[6];
  const float* xp_w     = (const float*)d_in[7];
  const float* conv_w   = (const float*)d_in[8];
  const float* conv_b   = (const float*)d_in[9];
  const float* out_w    = (const float*)d_in[10];
  const float* ng       = (const float*)d_in[11];
  const float* nb       = (const float*)d_in[12];
  const float* fw1      = (const float*)d_in[13];
  const float* fb1      = (const float*)d_in[14];
  const float* fw2      = (const float*)d_in[15];
  const float* fb2      = (const float*)d_in[16];
  const float* flg      = (const float*)d_in[17];
  const float* flb      = (const float*)d_in[18];
  const float* alt_embed= (const float*)d_in[19];
  const float* gate_w   = (const float*)d_in[20];
  const float* gate_b   = (const float*)d_in[21];
  float* out = (float*)d_out;

  float* p = (float*)d_ws;
  float* x_buf = p; p += (long)BL * DD;
  float* xdbl  = p; p += 4L * BL * 48;
  float* opre  = p; p += 4L * BL * DD;
  float* h2    = p; p += (long)BL * DD;
  float* gateb = p; p += 2L * BB * DD;
  float* aexp  = p; p += (long)NL * NDIR * DIN * NS;
  short* sp = (short*)p;
  short* wbf     = sp; sp += WTOT;
  short* xinb    = sp; sp += 4L * BL * DIN;
  short* zbf     = sp; sp += 4L * BL * DIN;
  short* xcbf    = sp; sp += 4L * BL * DIN;
  short* ybf     = sp; sp += 4L * BL * DIN;
  short* comb_bf = sp; sp += (long)BL * 1024;
  short* hfu_bf  = sp; sp += (long)BL * 512;

  k_transpose<<<2048, 256, 0, stream>>>(feat, x_buf);
  k_gate<<<16, 256, 0, stream>>>(alt_embed, alt_idx, gate_w, gate_b, gateb);
  k_aexp<<<256, 256, 0, stream>>>(A_log, aexp);
  k_wcvt<<<4544, 256, 0, stream>>>(in_w, xp_w, out_w, fw1, fw2, wbf);

  for (int li = 0; li < NL; li++){
    // xz = perm(x) @ in_w^T  (M=2048, N=1024, K=256, batch 4 dirs; split epilogue: x_in bf16, z silu bf16)
    k_mgemm<2, 2, 2, false, false, 1><<<dim3(16, 8, 4), 256, 0, stream>>>(
        x_buf, wbf + WOFF_IN + (long)li * NDIR * 1024 * 256, nullptr, xinb, zbf,
        BL, 1024, 256, 0, 1024L * 256, (long)BL * DIN);
    k_conv<<<dim3(8, 2, 32), 256, 0, stream>>>(xinb, conv_w + (long)li * NDIR * DIN * 4,
                                               conv_b + (long)li * NDIR * DIN, xcbf);
    // x_dbl = x_conv @ xp_w^T  (M=2048, N=48, K=512, batch 4)
    k_mgemm<4, 1, 0, false, false, 0><<<dim3(8, 1, 4), 256, 0, stream>>>(
        xcbf, wbf + WOFF_XP + (long)li * NDIR * 48 * 512, nullptr, xdbl, nullptr,
        BL, 48, 512, (long)BL * DIN, 48L * 512, (long)BL * 48);
    k_scan<<<dim3(64, 8, 4), 512, 0, stream>>>(xcbf, zbf, xdbl,
        aexp + (long)li * NDIR * DIN * NS,
        dt_w + (long)li * NDIR * DIN * 16, dt_b + (long)li * NDIR * DIN,
        Dp + (long)li * NDIR * DIN, ybf);
    // out_pre = y @ out_w^T  (M=2048, N=256, K=512, batch 4)
    k_mgemm<2, 2, 0, false, false, 0><<<dim3(16, 2, 4), 256, 0, stream>>>(
        ybf, wbf + WOFF_OUT + (long)li * NDIR * 256 * 512, nullptr, opre, nullptr,
        BL, 256, 512, (long)BL * DIN, 256L * 512, (long)BL * 256);
    k_ln1<<<dim3(256, 8, 4), 256, 0, stream>>>(opre, x_buf, ng + (long)li * NDIR * DD,
                                               nb + (long)li * NDIR * DD, comb_bf);
    // hfu = gelu(comb @ fw1^T + fb1)  (M=2048, N=512, K=1024) -> bf16
    k_mgemm<2, 2, 1, true, true, 0><<<dim3(16, 4, 1), 256, 0, stream>>>(
        comb_bf, wbf + WOFF_F1 + (long)li * 512 * 1024, fb1 + (long)li * 512, hfu_bf, nullptr,
        BL, 512, 1024, 0, 0, 0);
    // h2 = hfu @ fw2^T + fb2  (M=2048, N=256, K=512)
    k_mgemm<2, 2, 0, true, false, 0><<<dim3(16, 2, 1), 256, 0, stream>>>(
        hfu_bf, wbf + WOFF_F2 + (long)li * 256 * 512, fb2 + (long)li * 256, h2, nullptr,
        BL, 256, 512, 0, 0, 0);
    float* dst = (li == NL - 1) ? out : x_buf;
    k_ln2<<<dim3(256, 8), 256, 0, stream>>>(h2, flg + (long)li * DD, flb + (long)li * DD,
                                            gateb + (long)li * BB * DD, dst);
  }
}

// Round 8
// 562.065 us; speedup vs baseline: 1.0407x; 1.0407x over previous
//
#include <hip/hip_runtime.h>
#include <math.h>

// Problem constants
#define NL 2
#define NDIR 4
#define DD 256     // D (channels)
#define DIN 512    // DI (inner)
#define NS 16      // N (state)
#define BB 8       // batch
#define LL 256     // L = H*W
#define BL 2048    // B*L

typedef short s16x8 __attribute__((ext_vector_type(8)));
typedef short s16x4 __attribute__((ext_vector_type(4)));
typedef float f32x4 __attribute__((ext_vector_type(4)));

// fast-math device helpers (tolerance 4.56e-2 >> 2-ulp native error)
__device__ __forceinline__ float fsilu(float x){ return __fdividef(x, 1.f + __expf(-x)); }
__device__ __forceinline__ float fsigmoid(float x){ return __fdividef(1.f, 1.f + __expf(-x)); }
__device__ __forceinline__ float fsoftplus(float x){ return fmaxf(x, 0.f) + __logf(1.f + __expf(-fabsf(x))); }
__device__ __forceinline__ float geluf(float x){ return 0.5f * x * (1.f + erff(x * 0.70710678118654752f)); }
__device__ __forceinline__ short cvtbf(float f){
  unsigned u = __float_as_uint(f);
  u += 0x7FFF + ((u >> 16) & 1);
  return (short)(u >> 16);
}
__device__ __forceinline__ float bf2f(short s){
  return __uint_as_float(((unsigned)(unsigned short)s) << 16);
}
__device__ __forceinline__ int perml(int l, int d){
  int h = l >> 4, w = l & 15;
  if (d & 1) w = 15 - w;
  if (d & 2) h = 15 - h;
  return (h << 4) | w;
}

// feat (B,C,H,W) -> x (B,L,C)
__global__ __launch_bounds__(256) void k_transpose(const float* __restrict__ feat, float* __restrict__ x){
  int idx = blockIdx.x * 256 + threadIdx.x;
  int c = idx & 255, l = (idx >> 8) & 255, b = idx >> 16;
  x[idx] = feat[((b * DD + c) * 16 + (l >> 4)) * 16 + (l & 15)];
}

__global__ __launch_bounds__(256) void k_gate(const float* __restrict__ alt_embed, const int* __restrict__ alt_idx,
                      const float* __restrict__ gate_w, const float* __restrict__ gate_b,
                      float* __restrict__ gate){
  int idx = blockIdx.x * 256 + threadIdx.x;
  int c = idx & 255, b = (idx >> 8) & 7, li = idx >> 11;
  const float* ae = alt_embed + alt_idx[b] * 32;
  const float* gw = gate_w + ((long)li * DD + c) * 32;
  float acc = gate_b[li * DD + c];
  #pragma unroll
  for (int j = 0; j < 32; j++) acc += ae[j] * gw[j];
  gate[idx] = fsigmoid(acc);
}

// Aexp = -exp(A_log), whole tensor (65536)
__global__ __launch_bounds__(256) void k_aexp(const float* __restrict__ A_log, float* __restrict__ Aexp){
  int idx = blockIdx.x * 256 + threadIdx.x;
  Aexp[idx] = -expf(A_log[idx]);
}

// Convert all 5 GEMM weight tensors fp32->bf16 into one pool
#define WOFF_IN   0L
#define WOFF_XP   2097152L
#define WOFF_OUT  2293760L
#define WOFF_F1   3342336L
#define WOFF_F2   4390912L
#define WTOT      4653056L
__global__ __launch_bounds__(256) void k_wcvt(const float* __restrict__ s0, const float* __restrict__ s1,
      const float* __restrict__ s2, const float* __restrict__ s3, const float* __restrict__ s4,
      short* __restrict__ dst){
  long e = ((long)blockIdx.x * 256 + threadIdx.x) * 4;
  const float* src; long off;
  if      (e < WOFF_XP) { src = s0; off = e; }
  else if (e < WOFF_OUT){ src = s1; off = e - WOFF_XP; }
  else if (e < WOFF_F1) { src = s2; off = e - WOFF_OUT; }
  else if (e < WOFF_F2) { src = s3; off = e - WOFF_F1; }
  else                  { src = s4; off = e - WOFF_F2; }
  f32x4 v = *(const f32x4*)(src + off);
  s16x4 o = { cvtbf(v[0]), cvtbf(v[1]), cvtbf(v[2]), cvtbf(v[3]) };
  *(s16x4*)(dst + e) = o;
}

// Build combined xp+dt weight per (li,d): rows 0:32 = xp_w[16:48] (B,C proj);
// rows 32:544 = Wdt[i,k] = sum_s dt_w[i,s]*xp_w[s,k]  (composed dt projection)
#define NXP2 544
__global__ __launch_bounds__(256) void k_wxp(const float* __restrict__ xp_w, const float* __restrict__ dt_w,
                                             short* __restrict__ wxp2){
  long e = (long)blockIdx.x * 256 + threadIdx.x;   // NL*NDIR*544*512 = 2,228,224
  int k = (int)(e & 511);
  long t = e >> 9;
  int r = (int)(t % NXP2);
  int g = (int)(t / NXP2);                          // li*4+d
  const float* xw = xp_w + (long)g * 48 * 512;
  float val;
  if (r < 32){
    val = xw[(long)(16 + r) * 512 + k];
  } else {
    const float* dw = dt_w + ((long)g * 512 + (r - 32)) * 16;
    float acc = 0.f;
    #pragma unroll
    for (int s = 0; s < 16; s++) acc += dw[s] * xw[(long)s * 512 + k];
    val = acc;
  }
  wxp2[e] = cvtbf(val);
}

// MFMA bf16 GEMM: C[m,n] = act(sum_k A[m,k]*W[n,k] + bias[n])
// W: bf16 (N,K). ALAY 0: A bf16 row-major. ALAY 1: A fp32 gathered from x (B,L,C) via perml(dir=blockIdx.z).
// ACT: 0 none, 1 gelu, 2 split-silu-bf16 (n<512 raw bf16->Cv, n>=512 silu bf16->Cv2)
// ACT 3: xp+dt split — n<32 fp32->Cv (stride 32); n>=32 softplus(v + bias[d*512+n-32]) bf16->Cv2 (stride 512)
template<int WM, int WN, int ACT, bool BIAS, bool OBF, int ALAY>
__global__ __launch_bounds__(256) void k_mgemm(const void* __restrict__ Av, const short* __restrict__ W,
        const float* __restrict__ bias, void* __restrict__ Cv, void* __restrict__ Cv2,
        int M, int N, int K, long aB, long wB, long cB){
  constexpr int TM = WM * 64, TN = WN * 64;
  __shared__ short As[TM][40];
  __shared__ short Ws[TN][40];
  int m0 = blockIdx.x * TM, n0 = blockIdx.y * TN, d = blockIdx.z;
  int t = threadIdx.x;
  int wave = t >> 6, lane = t & 63;
  int wr = wave / WN, wc = wave % WN;
  int lq = lane >> 4, lr = lane & 15;
  const short* Wd = W + (long)d * wB;
  f32x4 acc[4][4];
  #pragma unroll
  for (int i = 0; i < 4; i++)
    #pragma unroll
    for (int j = 0; j < 4; j++) acc[i][j] = (f32x4){0.f, 0.f, 0.f, 0.f};

  for (int kb = 0; kb < K; kb += 32){
    if (ALAY == 0){
      const short* Ad = (const short*)Av + (long)d * aB;
      #pragma unroll
      for (int r = 0; r < WM; r++){
        int e = r * 256 + t;
        int row = e >> 2, c8 = e & 3;
        s16x8 v = *(const s16x8*)(Ad + (long)(m0 + row) * K + kb + c8 * 8);
        *(s16x8*)&As[row][c8 * 8] = v;
      }
    } else {
      const float* Aq = (const float*)Av;
      #pragma unroll
      for (int r = 0; r < 2 * WM; r++){
        int e = r * 256 + t;
        int row = e >> 3, c4 = e & 7;
        int m = m0 + row;
        const float* src = Aq + ((long)((m >> 8) << 8) + perml(m & 255, d)) * 256 + kb + c4 * 4;
        f32x4 v = *(const f32x4*)src;
        s16x4 sv = { cvtbf(v[0]), cvtbf(v[1]), cvtbf(v[2]), cvtbf(v[3]) };
        *(s16x4*)&As[row][c4 * 4] = sv;
      }
    }
    #pragma unroll
    for (int r = 0; r < WN; r++){
      int e = r * 256 + t;
      int row = e >> 2, c8 = e & 3;
      int n = n0 + row;
      s16x8 v = (s16x8){0,0,0,0,0,0,0,0};
      if (n < N) v = *(const s16x8*)(Wd + (long)n * K + kb + c8 * 8);
      *(s16x8*)&Ws[row][c8 * 8] = v;
    }
    __syncthreads();
    s16x8 af[4], wf[4];
    #pragma unroll
    for (int mi = 0; mi < 4; mi++) af[mi] = *(const s16x8*)&As[wr * 64 + mi * 16 + lr][lq * 8];
    #pragma unroll
    for (int ni = 0; ni < 4; ni++) wf[ni] = *(const s16x8*)&Ws[wc * 64 + ni * 16 + lr][lq * 8];
    #pragma unroll
    for (int mi = 0; mi < 4; mi++)
      #pragma unroll
      for (int ni = 0; ni < 4; ni++)
        acc[mi][ni] = __builtin_amdgcn_mfma_f32_16x16x32_bf16(af[mi], wf[ni], acc[mi][ni], 0, 0, 0);
    __syncthreads();
  }

  #pragma unroll
  for (int mi = 0; mi < 4; mi++){
    #pragma unroll
    for (int ni = 0; ni < 4; ni++){
      int n = n0 + wc * 64 + ni * 16 + lr;
      if (n < N){
        float bv = BIAS ? bias[n] : 0.f;
        #pragma unroll
        for (int r = 0; r < 4; r++){
          int m = m0 + wr * 64 + mi * 16 + lq * 4 + r;
          float v = acc[mi][ni][r] + bv;
          if (ACT == 1) v = geluf(v);
          if (ACT == 2){
            if (n < DIN) ((short*)Cv )[(long)d * cB + (long)m * DIN + n]         = cvtbf(v);
            else         ((short*)Cv2)[(long)d * cB + (long)m * DIN + (n - DIN)] = cvtbf(fsilu(v));
          } else if (ACT == 3){
            if (n < 32) ((float*)Cv)[((long)d * BL + m) * 32 + n] = v;
            else {
              float dv = fsoftplus(v + bias[(long)d * DIN + (n - 32)]);
              ((short*)Cv2)[((long)d * BL + m) * DIN + (n - 32)] = cvtbf(dv);
            }
          } else {
            if (OBF) ((short*)Cv)[(long)d * cB + (long)m * N + n] = cvtbf(v);
            else     ((float*)Cv)[(long)d * cB + (long)m * N + n] = v;
          }
        }
      }
    }
  }
}

// causal depthwise conv (K=4) + silu on bf16 xinb[db,l,512]; writes bf16 xcbf[db,l,i]
__global__ __launch_bounds__(256) void k_conv(const short* __restrict__ xinb, const float* __restrict__ cw,
                      const float* __restrict__ cb, short* __restrict__ xcbf){
  int it = blockIdx.x * 64, lc = blockIdx.y * 128, db = blockIdx.z;
  int d = db >> 3;
  int t = threadIdx.x;
  __shared__ float xs[64][131];
  const short* src = xinb + (long)db * LL * DIN;
  for (int e = t; e < 131 * 64; e += 256){
    int il = e & 63, lh = e >> 6;
    int gl = lc - 3 + lh;
    xs[il][lh] = (gl >= 0) ? bf2f(src[(long)gl * DIN + it + il]) : 0.f;
  }
  __syncthreads();
  const float* cwp = cw + ((long)d * DIN + it) * 4;
  const float* cbp = cb + (long)d * DIN + it;
  for (int e = t; e < 64 * 128; e += 256){
    int il = e & 63, lh = e >> 6;
    float acc = cbp[il];
    #pragma unroll
    for (int k = 0; k < 4; k++) acc += xs[il][lh + k] * cwp[il * 4 + k];
    xcbf[((long)db * LL + lc + lh) * DIN + it + il] = cvtbf(fsilu(acc));
  }
}

// windowed scan (K=8) — chunked, LDS-free, native exp, dt precomputed (bf16).
// Thread = (i, s-half) for one 8-l chunk [bs, bs+7].
__global__ __launch_bounds__(512) void k_scan(
    const short* __restrict__ xcbf, const short* __restrict__ zbf,
    const short* __restrict__ dtbf, const float* __restrict__ xdbl,
    const float* __restrict__ Aexp, const float* __restrict__ Dp,
    short* __restrict__ ybf){
  int bx = blockIdx.x;
  int itile = bx & 1, chunk = bx >> 1;
  int b = blockIdx.y, d = blockIdx.z;
  int db = d * BB + b;
  int tid = threadIdx.x;
  int half = tid & 1;
  int i = itile * 256 + (tid >> 1);
  int bs = chunk * 8;
  const float* alp = Aexp + ((long)(d * DIN + i)) * 16 + half * 8;
  float A[8];
  *(f32x4*)&A[0] = *(const f32x4*)(alp);
  *(f32x4*)&A[4] = *(const f32x4*)(alp + 4);
  float Di = Dp[d * DIN + i];
  const float* xdb = xdbl + (long)db * LL * 32;
  long pix = (long)db * LL * DIN + i;   // + l*DIN

  float T[8], R[7][8], P[8];
  #pragma unroll
  for (int s = 0; s < 8; s++){ T[s] = 0.f; P[s] = 1.f; }
  if (bs > 0){
    #pragma unroll
    for (int m = 1; m <= 7; m++){
      int j = bs - m;
      float dt = bf2f(dtbf[pix + (long)j * DIN]);
      float xc = bf2f(xcbf[pix + (long)j * DIN]);
      float dx = dt * xc;
      const float* bp = xdb + j * 32 + half * 8;
      f32x4 b0 = *(const f32x4*)bp, b1 = *(const f32x4*)(bp + 4);
      #pragma unroll
      for (int s = 0; s < 8; s++){
        float Bv = (s < 4) ? b0[s] : b1[s - 4];
        float E = __expf(A[s] * dt);
        float Rv = P[s] * (dx * Bv);
        R[m - 1][s] = Rv;
        T[s] += Rv;
        P[s] *= E;
      }
    }
  } else {
    #pragma unroll
    for (int m = 0; m < 7; m++)
      #pragma unroll
      for (int s = 0; s < 8; s++) R[m][s] = 0.f;
  }
  float h[8], Q[8];
  #pragma unroll
  for (int s = 0; s < 8; s++){ h[s] = 0.f; Q[s] = 1.f; }
  #pragma unroll
  for (int r = 0; r < 8; r++){
    int l = bs + r;
    float dt = bf2f(dtbf[pix + (long)l * DIN]);
    float xc = bf2f(xcbf[pix + (long)l * DIN]);
    float z  = bf2f(zbf [pix + (long)l * DIN]);
    float dx = dt * xc;
    const float* bp = xdb + l * 32 + half * 8;
    f32x4 b0 = *(const f32x4*)bp, b1 = *(const f32x4*)(bp + 4);
    f32x4 c0 = *(const f32x4*)(bp + 16), c1 = *(const f32x4*)(bp + 20);
    float y = 0.f;
    #pragma unroll
    for (int s = 0; s < 8; s++){
      float Bv = (s < 4) ? b0[s] : b1[s - 4];
      float Cv = (s < 4) ? c0[s] : c1[s - 4];
      float E = __expf(A[s] * dt);
      h[s] = E * h[s] + dx * Bv;
      Q[s] *= E;
      y += Cv * (h[s] + Q[s] * T[s]);
    }
    y += __shfl_xor(y, 1);
    if (half == 0){
      float outv = (y + Di * xc) * z;
      ybf[pix + (long)l * DIN] = cvtbf(outv);
    }
    if (r < 7){
      #pragma unroll
      for (int s = 0; s < 8; s++) T[s] -= R[6 - r][s];
    }
  }
}

// LN over C of (out_pre + residual from x via perml), write unflipped bf16 comb[b,t,d*256+c]
__global__ __launch_bounds__(256) void k_ln1(const float* __restrict__ out_pre, const float* __restrict__ x,
        const float* __restrict__ ng, const float* __restrict__ nb, short* __restrict__ comb_bf){
  int l = blockIdx.x, b = blockIdx.y, d = blockIdx.z, c = threadIdx.x;
  long row = ((long)(d * BB + b) * LL + l) * DD;
  int pl = perml(l, d);
  float v = out_pre[row + c] + x[((long)(b * LL) + pl) * DD + c];
  float s = v, q = v * v;
  #pragma unroll
  for (int off = 32; off; off >>= 1){ s += __shfl_down(s, off); q += __shfl_down(q, off); }
  __shared__ float ps[4], pq[4], mv[2];
  int wid = c >> 6;
  if ((c & 63) == 0){ ps[wid] = s; pq[wid] = q; }
  __syncthreads();
  if (c == 0){
    float ts = ps[0] + ps[1] + ps[2] + ps[3];
    float tq = pq[0] + pq[1] + pq[2] + pq[3];
    float m = ts / 256.f;
    mv[0] = m; mv[1] = rsqrtf(tq / 256.f - m * m + 1e-5f);
  }
  __syncthreads();
  float o = (v - mv[0]) * mv[1] * ng[d * DD + c] + nb[d * DD + c];
  comb_bf[((long)b * LL + pl) * 1024 + d * DD + c] = cvtbf(o);
}

// LN over C + gate multiply
__global__ __launch_bounds__(256) void k_ln2(const float* __restrict__ h2, const float* __restrict__ lg,
        const float* __restrict__ lb, const float* __restrict__ gate, float* __restrict__ dst){
  int l = blockIdx.x, b = blockIdx.y, c = threadIdx.x;
  long row = ((long)b * LL + l) * DD;
  float v = h2[row + c];
  float s = v, q = v * v;
  #pragma unroll
  for (int off = 32; off; off >>= 1){ s += __shfl_down(s, off); q += __shfl_down(q, off); }
  __shared__ float ps[4], pq[4], mv[2];
  int wid = c >> 6;
  if ((c & 63) == 0){ ps[wid] = s; pq[wid] = q; }
  __syncthreads();
  if (c == 0){
    float ts = ps[0] + ps[1] + ps[2] + ps[3];
    float tq = pq[0] + pq[1] + pq[2] + pq[3];
    float m = ts / 256.f;
    mv[0] = m; mv[1] = rsqrtf(tq / 256.f - m * m + 1e-5f);
  }
  __syncthreads();
  float o = (v - mv[0]) * mv[1] * lg[c] + lb[c];
  dst[row + c] = o * gate[b * DD + c];
}

extern "C" void kernel_launch(void* const* d_in, const int* in_sizes, int n_in,
                              void* d_out, int out_size, void* d_ws, size_t ws_size,
                              hipStream_t stream){
  const float* feat     = (const float*)d_in[0];
  const int*   alt_idx  = (const int*)d_in[1];
  const float* in_w     = (const float*)d_in[2];
  const float* dt_w     = (const float*)d_in[3];
  const float* dt_b     = (const float*)d_in[4];
  const float* A_log    = (const float*)d_in[5];
  const float* Dp       = (const float*)d_in[6];
  const float* xp_w     = (const float*)d_in[7];
  const float* conv_w   = (const float*)d_in[8];
  const float* conv_b   = (const float*)d_in[9];
  const float* out_w    = (const float*)d_in[10];
  const float* ng       = (const float*)d_in[11];
  const float* nb       = (const float*)d_in[12];
  const float* fw1      = (const float*)d_in[13];
  const float* fb1      = (const float*)d_in[14];
  const float* fw2      = (const float*)d_in[15];
  const float* fb2      = (const float*)d_in[16];
  const float* flg      = (const float*)d_in[17];
  const float* flb      = (const float*)d_in[18];
  const float* alt_embed= (const float*)d_in[19];
  const float* gate_w   = (const float*)d_in[20];
  const float* gate_b   = (const float*)d_in[21];
  float* out = (float*)d_out;

  float* p = (float*)d_ws;
  float* x_buf = p; p += (long)BL * DD;
  float* xdbl  = p; p += 4L * BL * 32;
  float* opre  = p; p += 4L * BL * DD;
  float* h2    = p; p += (long)BL * DD;
  float* gateb = p; p += 2L * BB * DD;
  float* aexp  = p; p += (long)NL * NDIR * DIN * NS;
  short* sp = (short*)p;
  short* wbf     = sp; sp += WTOT;
  short* wxp2    = sp; sp += (long)NL * NDIR * NXP2 * 512;
  short* xinb    = sp; sp += 4L * BL * DIN;
  short* zbf     = sp; sp += 4L * BL * DIN;
  short* xcbf    = sp; sp += 4L * BL * DIN;
  short* dtbf    = sp; sp += 4L * BL * DIN;
  short* ybf     = sp; sp += 4L * BL * DIN;
  short* comb_bf = sp; sp += (long)BL * 1024;
  short* hfu_bf  = sp; sp += (long)BL * 512;

  k_transpose<<<2048, 256, 0, stream>>>(feat, x_buf);
  k_gate<<<16, 256, 0, stream>>>(alt_embed, alt_idx, gate_w, gate_b, gateb);
  k_aexp<<<256, 256, 0, stream>>>(A_log, aexp);
  k_wcvt<<<4544, 256, 0, stream>>>(in_w, xp_w, out_w, fw1, fw2, wbf);
  k_wxp<<<8704, 256, 0, stream>>>(xp_w, dt_w, wxp2);   // NL*NDIR*544*512 / 256

  for (int li = 0; li < NL; li++){
    // xz = perm(x) @ in_w^T  (M=2048, N=1024, K=256, batch 4 dirs; split epilogue: x_in bf16, z silu bf16)
    k_mgemm<2, 2, 2, false, false, 1><<<dim3(16, 8, 4), 256, 0, stream>>>(
        x_buf, wbf + WOFF_IN + (long)li * NDIR * 1024 * 256, nullptr, xinb, zbf,
        BL, 1024, 256, 0, 1024L * 256, (long)BL * DIN);
    k_conv<<<dim3(8, 2, 32), 256, 0, stream>>>(xinb, conv_w + (long)li * NDIR * DIN * 4,
                                               conv_b + (long)li * NDIR * DIN, xcbf);
    // [B,C | dt] = x_conv @ wxp2^T  (M=2048, N=544, K=512, batch 4; epilogue splits fp32 B,C / softplus bf16 dt)
    k_mgemm<4, 1, 3, false, false, 0><<<dim3(8, 9, 4), 256, 0, stream>>>(
        xcbf, wxp2 + (long)li * NDIR * NXP2 * 512, dt_b + (long)li * NDIR * DIN, xdbl, dtbf,
        BL, NXP2, 512, (long)BL * DIN, (long)NXP2 * 512, 0);
    k_scan<<<dim3(64, 8, 4), 512, 0, stream>>>(xcbf, zbf, dtbf, xdbl,
        aexp + (long)li * NDIR * DIN * NS, Dp + (long)li * NDIR * DIN, ybf);
    // out_pre = y @ out_w^T  (M=2048, N=256, K=512, batch 4)
    k_mgemm<2, 2, 0, false, false, 0><<<dim3(16, 2, 4), 256, 0, stream>>>(
        ybf, wbf + WOFF_OUT + (long)li * NDIR * 256 * 512, nullptr, opre, nullptr,
        BL, 256, 512, (long)BL * DIN, 256L * 512, (long)BL * 256);
    k_ln1<<<dim3(256, 8, 4), 256, 0, stream>>>(opre, x_buf, ng + (long)li * NDIR * DD,
                                               nb + (long)li * NDIR * DD, comb_bf);
    // hfu = gelu(comb @ fw1^T + fb1)  (M=2048, N=512, K=1024) -> bf16
    k_mgemm<2, 2, 1, true, true, 0><<<dim3(16, 4, 1), 256, 0, stream>>>(
        comb_bf, wbf + WOFF_F1 + (long)li * 512 * 1024, fb1 + (long)li * 512, hfu_bf, nullptr,
        BL, 512, 1024, 0, 0, 0);
    // h2 = hfu @ fw2^T + fb2  (M=2048, N=256, K=512)
    k_mgemm<2, 2, 0, true, false, 0><<<dim3(16, 2, 1), 256, 0, stream>>>(
        hfu_bf, wbf + WOFF_F2 + (long)li * 256 * 512, fb2 + (long)li * 256, h2, nullptr,
        BL, 256, 512, 0, 0, 0);
    float* dst = (li == NL - 1) ? out : x_buf;
    k_ln2<<<dim3(256, 8), 256, 0, stream>>>(h2, flg + (long)li * DD, flb + (long)li * DD,
                                            gateb + (long)li * BB * DD, dst);
  }
}

// Round 9
// 530.442 us; speedup vs baseline: 1.1028x; 1.0596x over previous
//
#include <hip/hip_runtime.h>
#include <math.h>

// Problem constants
#define NL 2
#define NDIR 4
#define DD 256     // D (channels)
#define DIN 512    // DI (inner)
#define NS 16      // N (state)
#define BB 8       // batch
#define LL 256     // L = H*W
#define BL 2048    // B*L

typedef short s16x8 __attribute__((ext_vector_type(8)));
typedef short s16x4 __attribute__((ext_vector_type(4)));
typedef float f32x4 __attribute__((ext_vector_type(4)));

// fast-math device helpers (tolerance 4.56e-2 >> 2-ulp native error)
__device__ __forceinline__ float fsilu(float x){ return __fdividef(x, 1.f + __expf(-x)); }
__device__ __forceinline__ float fsigmoid(float x){ return __fdividef(1.f, 1.f + __expf(-x)); }
__device__ __forceinline__ float fsoftplus(float x){ return fmaxf(x, 0.f) + __logf(1.f + __expf(-fabsf(x))); }
__device__ __forceinline__ float geluf(float x){ return 0.5f * x * (1.f + erff(x * 0.70710678118654752f)); }
__device__ __forceinline__ short cvtbf(float f){
  unsigned u = __float_as_uint(f);
  u += 0x7FFF + ((u >> 16) & 1);
  return (short)(u >> 16);
}
__device__ __forceinline__ float bf2f(short s){
  return __uint_as_float(((unsigned)(unsigned short)s) << 16);
}
__device__ __forceinline__ int perml(int l, int d){
  int h = l >> 4, w = l & 15;
  if (d & 1) w = 15 - w;
  if (d & 2) h = 15 - h;
  return (h << 4) | w;
}

// feat (B,C,H,W) -> x (B,L,C)
__global__ __launch_bounds__(256) void k_transpose(const float* __restrict__ feat, float* __restrict__ x){
  int idx = blockIdx.x * 256 + threadIdx.x;
  int c = idx & 255, l = (idx >> 8) & 255, b = idx >> 16;
  x[idx] = feat[((b * DD + c) * 16 + (l >> 4)) * 16 + (l & 15)];
}

__global__ __launch_bounds__(256) void k_gate(const float* __restrict__ alt_embed, const int* __restrict__ alt_idx,
                      const float* __restrict__ gate_w, const float* __restrict__ gate_b,
                      float* __restrict__ gate){
  int idx = blockIdx.x * 256 + threadIdx.x;
  int c = idx & 255, b = (idx >> 8) & 7, li = idx >> 11;
  const float* ae = alt_embed + alt_idx[b] * 32;
  const float* gw = gate_w + ((long)li * DD + c) * 32;
  float acc = gate_b[li * DD + c];
  #pragma unroll
  for (int j = 0; j < 32; j++) acc += ae[j] * gw[j];
  gate[idx] = fsigmoid(acc);
}

// Aexp = -exp(A_log), whole tensor (65536)
__global__ __launch_bounds__(256) void k_aexp(const float* __restrict__ A_log, float* __restrict__ Aexp){
  int idx = blockIdx.x * 256 + threadIdx.x;
  Aexp[idx] = -expf(A_log[idx]);
}

// Convert all 5 GEMM weight tensors fp32->bf16 into one pool
#define WOFF_IN   0L
#define WOFF_XP   2097152L
#define WOFF_OUT  2293760L
#define WOFF_F1   3342336L
#define WOFF_F2   4390912L
#define WTOT      4653056L
__global__ __launch_bounds__(256) void k_wcvt(const float* __restrict__ s0, const float* __restrict__ s1,
      const float* __restrict__ s2, const float* __restrict__ s3, const float* __restrict__ s4,
      short* __restrict__ dst){
  long e = ((long)blockIdx.x * 256 + threadIdx.x) * 4;
  const float* src; long off;
  if      (e < WOFF_XP) { src = s0; off = e; }
  else if (e < WOFF_OUT){ src = s1; off = e - WOFF_XP; }
  else if (e < WOFF_F1) { src = s2; off = e - WOFF_OUT; }
  else if (e < WOFF_F2) { src = s3; off = e - WOFF_F1; }
  else                  { src = s4; off = e - WOFF_F2; }
  f32x4 v = *(const f32x4*)(src + off);
  s16x4 o = { cvtbf(v[0]), cvtbf(v[1]), cvtbf(v[2]), cvtbf(v[3]) };
  *(s16x4*)(dst + e) = o;
}

// Build combined xp+dt weight per (li,d): rows 0:32 = xp_w[16:48]; rows 32:544 = dt_w @ xp_w[0:16]
#define NXP2 544
__global__ __launch_bounds__(256) void k_wxp(const float* __restrict__ xp_w, const float* __restrict__ dt_w,
                                             short* __restrict__ wxp2){
  long e = (long)blockIdx.x * 256 + threadIdx.x;   // NL*NDIR*544*512
  int k = (int)(e & 511);
  long t = e >> 9;
  int r = (int)(t % NXP2);
  int g = (int)(t / NXP2);                          // li*4+d
  const float* xw = xp_w + (long)g * 48 * 512;
  float val;
  if (r < 32){
    val = xw[(long)(16 + r) * 512 + k];
  } else {
    const float* dw = dt_w + ((long)g * 512 + (r - 32)) * 16;
    float acc = 0.f;
    #pragma unroll
    for (int s = 0; s < 16; s++) acc += dw[s] * xw[(long)s * 512 + k];
    val = acc;
  }
  wxp2[e] = cvtbf(val);
}

// MFMA bf16 GEMM: C[m,n] = act(sum_k A[m,k]*W[n,k] + bias[n])
// ACT: 0 none, 1 gelu, 2 split-silu-bf16, 3 xp+dt split
template<int WM, int WN, int ACT, bool BIAS, bool OBF, int ALAY>
__global__ __launch_bounds__(256) void k_mgemm(const void* __restrict__ Av, const short* __restrict__ W,
        const float* __restrict__ bias, void* __restrict__ Cv, void* __restrict__ Cv2,
        int M, int N, int K, long aB, long wB, long cB){
  constexpr int TM = WM * 64, TN = WN * 64;
  __shared__ short As[TM][40];
  __shared__ short Ws[TN][40];
  int m0 = blockIdx.x * TM, n0 = blockIdx.y * TN, d = blockIdx.z;
  int t = threadIdx.x;
  int wave = t >> 6, lane = t & 63;
  int wr = wave / WN, wc = wave % WN;
  int lq = lane >> 4, lr = lane & 15;
  const short* Wd = W + (long)d * wB;
  f32x4 acc[4][4];
  #pragma unroll
  for (int i = 0; i < 4; i++)
    #pragma unroll
    for (int j = 0; j < 4; j++) acc[i][j] = (f32x4){0.f, 0.f, 0.f, 0.f};

  for (int kb = 0; kb < K; kb += 32){
    if (ALAY == 0){
      const short* Ad = (const short*)Av + (long)d * aB;
      #pragma unroll
      for (int r = 0; r < WM; r++){
        int e = r * 256 + t;
        int row = e >> 2, c8 = e & 3;
        s16x8 v = *(const s16x8*)(Ad + (long)(m0 + row) * K + kb + c8 * 8);
        *(s16x8*)&As[row][c8 * 8] = v;
      }
    } else {
      const float* Aq = (const float*)Av;
      #pragma unroll
      for (int r = 0; r < 2 * WM; r++){
        int e = r * 256 + t;
        int row = e >> 3, c4 = e & 7;
        int m = m0 + row;
        const float* src = Aq + ((long)((m >> 8) << 8) + perml(m & 255, d)) * 256 + kb + c4 * 4;
        f32x4 v = *(const f32x4*)src;
        s16x4 sv = { cvtbf(v[0]), cvtbf(v[1]), cvtbf(v[2]), cvtbf(v[3]) };
        *(s16x4*)&As[row][c4 * 4] = sv;
      }
    }
    #pragma unroll
    for (int r = 0; r < WN; r++){
      int e = r * 256 + t;
      int row = e >> 2, c8 = e & 3;
      int n = n0 + row;
      s16x8 v = (s16x8){0,0,0,0,0,0,0,0};
      if (n < N) v = *(const s16x8*)(Wd + (long)n * K + kb + c8 * 8);
      *(s16x8*)&Ws[row][c8 * 8] = v;
    }
    __syncthreads();
    s16x8 af[4], wf[4];
    #pragma unroll
    for (int mi = 0; mi < 4; mi++) af[mi] = *(const s16x8*)&As[wr * 64 + mi * 16 + lr][lq * 8];
    #pragma unroll
    for (int ni = 0; ni < 4; ni++) wf[ni] = *(const s16x8*)&Ws[wc * 64 + ni * 16 + lr][lq * 8];
    #pragma unroll
    for (int mi = 0; mi < 4; mi++)
      #pragma unroll
      for (int ni = 0; ni < 4; ni++)
        acc[mi][ni] = __builtin_amdgcn_mfma_f32_16x16x32_bf16(af[mi], wf[ni], acc[mi][ni], 0, 0, 0);
    __syncthreads();
  }

  #pragma unroll
  for (int mi = 0; mi < 4; mi++){
    #pragma unroll
    for (int ni = 0; ni < 4; ni++){
      int n = n0 + wc * 64 + ni * 16 + lr;
      if (n < N){
        float bv = BIAS ? bias[n] : 0.f;
        #pragma unroll
        for (int r = 0; r < 4; r++){
          int m = m0 + wr * 64 + mi * 16 + lq * 4 + r;
          float v = acc[mi][ni][r] + bv;
          if (ACT == 1) v = geluf(v);
          if (ACT == 2){
            if (n < DIN) ((short*)Cv )[(long)d * cB + (long)m * DIN + n]         = cvtbf(v);
            else         ((short*)Cv2)[(long)d * cB + (long)m * DIN + (n - DIN)] = cvtbf(fsilu(v));
          } else if (ACT == 3){
            if (n < 32) ((float*)Cv)[((long)d * BL + m) * 32 + n] = v;
            else {
              float dv = fsoftplus(v + bias[(long)d * DIN + (n - 32)]);
              ((short*)Cv2)[((long)d * BL + m) * DIN + (n - 32)] = cvtbf(dv);
            }
          } else {
            if (OBF) ((short*)Cv)[(long)d * cB + (long)m * N + n] = cvtbf(v);
            else     ((float*)Cv)[(long)d * cB + (long)m * N + n] = v;
          }
        }
      }
    }
  }
}

// GEMM (M=2048 per batch, N=256, K=512) + full-row LayerNorm epilogue.
// Tile 64x256: 4 waves, wave wc owns cols [wc*64, wc*64+64).
// MODE 0: out-proj + residual(x via perml) + LN(ng,nb) -> comb_bf[b, pl, d*256+n] (bf16)
// MODE 1: fus2 + bias + LN(flg,flb) + gate -> dst fp32 [m*256+n]
template<int MODE>
__global__ __launch_bounds__(256) void k_gemmln(const short* __restrict__ A, const short* __restrict__ W,
        const float* __restrict__ bias, const float* __restrict__ aux,
        const float* __restrict__ g, const float* __restrict__ bvec,
        void* __restrict__ dst, long aB, long wB){
  __shared__ short As[64][40];
  __shared__ short Ws[256][40];
  __shared__ float ps[64][4], pq[64][4], mvm[64], mvr[64];
  int m0 = blockIdx.x * 64, d = blockIdx.z;
  int t = threadIdx.x;
  int wc = t >> 6, lane = t & 63;
  int lq = lane >> 4, lr = lane & 15;
  const short* Ad = A + (long)d * aB;
  const short* Wd = W + (long)d * wB;
  f32x4 acc[4][4];
  #pragma unroll
  for (int i = 0; i < 4; i++)
    #pragma unroll
    for (int j = 0; j < 4; j++) acc[i][j] = (f32x4){0.f, 0.f, 0.f, 0.f};

  for (int kb = 0; kb < 512; kb += 32){
    { int row = t >> 2, c8 = t & 3;
      *(s16x8*)&As[row][c8 * 8] = *(const s16x8*)(Ad + (long)(m0 + row) * 512 + kb + c8 * 8); }
    #pragma unroll
    for (int r = 0; r < 4; r++){
      int e = r * 256 + t;
      int row = e >> 2, c8 = e & 3;
      *(s16x8*)&Ws[row][c8 * 8] = *(const s16x8*)(Wd + (long)row * 512 + kb + c8 * 8);
    }
    __syncthreads();
    s16x8 af[4], wf[4];
    #pragma unroll
    for (int mi = 0; mi < 4; mi++) af[mi] = *(const s16x8*)&As[mi * 16 + lr][lq * 8];
    #pragma unroll
    for (int ni = 0; ni < 4; ni++) wf[ni] = *(const s16x8*)&Ws[wc * 64 + ni * 16 + lr][lq * 8];
    #pragma unroll
    for (int mi = 0; mi < 4; mi++)
      #pragma unroll
      for (int ni = 0; ni < 4; ni++)
        acc[mi][ni] = __builtin_amdgcn_mfma_f32_16x16x32_bf16(af[mi], wf[ni], acc[mi][ni], 0, 0, 0);
    __syncthreads();
  }

  // add residual (MODE0) or bias (MODE1) in place
  #pragma unroll
  for (int mi = 0; mi < 4; mi++){
    #pragma unroll
    for (int ni = 0; ni < 4; ni++){
      int n = wc * 64 + ni * 16 + lr;
      #pragma unroll
      for (int r = 0; r < 4; r++){
        int row = mi * 16 + lq * 4 + r;
        int m = m0 + row;
        float add;
        if (MODE == 0){
          int b = m >> 8, l = m & 255;
          add = aux[((long)b * LL + perml(l, d)) * DD + n];  // residual (aux = x_buf)
        } else {
          add = bias[n];
        }
        acc[mi][ni][r] += add;
      }
    }
  }
  // row stats: per-lane partial over ni, shfl_xor over lr, LDS over waves
  #pragma unroll
  for (int mi = 0; mi < 4; mi++){
    #pragma unroll
    for (int r = 0; r < 4; r++){
      float s = 0.f, q = 0.f;
      #pragma unroll
      for (int ni = 0; ni < 4; ni++){ float v = acc[mi][ni][r]; s += v; q += v * v; }
      #pragma unroll
      for (int mask = 1; mask <= 8; mask <<= 1){ s += __shfl_xor(s, mask); q += __shfl_xor(q, mask); }
      if (lr == 0){ int row = mi * 16 + lq * 4 + r; ps[row][wc] = s; pq[row][wc] = q; }
    }
  }
  __syncthreads();
  if (t < 64){
    float ts = ps[t][0] + ps[t][1] + ps[t][2] + ps[t][3];
    float tq = pq[t][0] + pq[t][1] + pq[t][2] + pq[t][3];
    float mean = ts * (1.f / 256.f);
    mvm[t] = mean;
    mvr[t] = rsqrtf(tq * (1.f / 256.f) - mean * mean + 1e-5f);
  }
  __syncthreads();
  #pragma unroll
  for (int mi = 0; mi < 4; mi++){
    #pragma unroll
    for (int ni = 0; ni < 4; ni++){
      int n = wc * 64 + ni * 16 + lr;
      #pragma unroll
      for (int r = 0; r < 4; r++){
        int row = mi * 16 + lq * 4 + r;
        int m = m0 + row;
        float o = (acc[mi][ni][r] - mvm[row]) * mvr[row] * g[d * DD + n] + bvec[d * DD + n];
        if (MODE == 0){
          int b = m >> 8, l = m & 255;
          ((short*)dst)[((long)b * LL + perml(l, d)) * 1024 + d * DD + n] = cvtbf(o);
        } else {
          int b = m >> 8;
          o *= aux[(long)b * DD + n];   // gate (aux = gateb slice)
          ((float*)dst)[(long)m * DD + n] = o;
        }
      }
    }
  }
}

// causal depthwise conv (K=4) + silu on bf16 xinb[db,l,512]; writes bf16 xcbf[db,l,i]
__global__ __launch_bounds__(256) void k_conv(const short* __restrict__ xinb, const float* __restrict__ cw,
                      const float* __restrict__ cb, short* __restrict__ xcbf){
  int it = blockIdx.x * 64, lc = blockIdx.y * 128, db = blockIdx.z;
  int d = db >> 3;
  int t = threadIdx.x;
  __shared__ float xs[64][131];
  const short* src = xinb + (long)db * LL * DIN;
  for (int e = t; e < 131 * 64; e += 256){
    int il = e & 63, lh = e >> 6;
    int gl = lc - 3 + lh;
    xs[il][lh] = (gl >= 0) ? bf2f(src[(long)gl * DIN + it + il]) : 0.f;
  }
  __syncthreads();
  const float* cwp = cw + ((long)d * DIN + it) * 4;
  const float* cbp = cb + (long)d * DIN + it;
  for (int e = t; e < 64 * 128; e += 256){
    int il = e & 63, lh = e >> 6;
    float acc = cbp[il];
    #pragma unroll
    for (int k = 0; k < 4; k++) acc += xs[il][lh + k] * cwp[il * 4 + k];
    xcbf[((long)db * LL + lc + lh) * DIN + it + il] = cvtbf(fsilu(acc));
  }
}

// windowed scan (K=8) — chunked, LDS-free, native exp, dt precomputed (bf16).
__global__ __launch_bounds__(512) void k_scan(
    const short* __restrict__ xcbf, const short* __restrict__ zbf,
    const short* __restrict__ dtbf, const float* __restrict__ xdbl,
    const float* __restrict__ Aexp, const float* __restrict__ Dp,
    short* __restrict__ ybf){
  int bx = blockIdx.x;
  int itile = bx & 1, chunk = bx >> 1;
  int b = blockIdx.y, d = blockIdx.z;
  int db = d * BB + b;
  int tid = threadIdx.x;
  int half = tid & 1;
  int i = itile * 256 + (tid >> 1);
  int bs = chunk * 8;
  const float* alp = Aexp + ((long)(d * DIN + i)) * 16 + half * 8;
  float A[8];
  *(f32x4*)&A[0] = *(const f32x4*)(alp);
  *(f32x4*)&A[4] = *(const f32x4*)(alp + 4);
  float Di = Dp[d * DIN + i];
  const float* xdb = xdbl + (long)db * LL * 32;
  long pix = (long)db * LL * DIN + i;   // + l*DIN

  float T[8], R[7][8], P[8];
  #pragma unroll
  for (int s = 0; s < 8; s++){ T[s] = 0.f; P[s] = 1.f; }
  if (bs > 0){
    #pragma unroll
    for (int m = 1; m <= 7; m++){
      int j = bs - m;
      float dt = bf2f(dtbf[pix + (long)j * DIN]);
      float xc = bf2f(xcbf[pix + (long)j * DIN]);
      float dx = dt * xc;
      const float* bp = xdb + j * 32 + half * 8;
      f32x4 b0 = *(const f32x4*)bp, b1 = *(const f32x4*)(bp + 4);
      #pragma unroll
      for (int s = 0; s < 8; s++){
        float Bv = (s < 4) ? b0[s] : b1[s - 4];
        float E = __expf(A[s] * dt);
        float Rv = P[s] * (dx * Bv);
        R[m - 1][s] = Rv;
        T[s] += Rv;
        P[s] *= E;
      }
    }
  } else {
    #pragma unroll
    for (int m = 0; m < 7; m++)
      #pragma unroll
      for (int s = 0; s < 8; s++) R[m][s] = 0.f;
  }
  float h[8], Q[8];
  #pragma unroll
  for (int s = 0; s < 8; s++){ h[s] = 0.f; Q[s] = 1.f; }
  #pragma unroll
  for (int r = 0; r < 8; r++){
    int l = bs + r;
    float dt = bf2f(dtbf[pix + (long)l * DIN]);
    float xc = bf2f(xcbf[pix + (long)l * DIN]);
    float z  = bf2f(zbf [pix + (long)l * DIN]);
    float dx = dt * xc;
    const float* bp = xdb + l * 32 + half * 8;
    f32x4 b0 = *(const f32x4*)bp, b1 = *(const f32x4*)(bp + 4);
    f32x4 c0 = *(const f32x4*)(bp + 16), c1 = *(const f32x4*)(bp + 20);
    float y = 0.f;
    #pragma unroll
    for (int s = 0; s < 8; s++){
      float Bv = (s < 4) ? b0[s] : b1[s - 4];
      float Cv = (s < 4) ? c0[s] : c1[s - 4];
      float E = __expf(A[s] * dt);
      h[s] = E * h[s] + dx * Bv;
      Q[s] *= E;
      y += Cv * (h[s] + Q[s] * T[s]);
    }
    y += __shfl_xor(y, 1);
    if (half == 0){
      float outv = (y + Di * xc) * z;
      ybf[pix + (long)l * DIN] = cvtbf(outv);
    }
    if (r < 7){
      #pragma unroll
      for (int s = 0; s < 8; s++) T[s] -= R[6 - r][s];
    }
  }
}

extern "C" void kernel_launch(void* const* d_in, const int* in_sizes, int n_in,
                              void* d_out, int out_size, void* d_ws, size_t ws_size,
                              hipStream_t stream){
  const float* feat     = (const float*)d_in[0];
  const int*   alt_idx  = (const int*)d_in[1];
  const float* in_w     = (const float*)d_in[2];
  const float* dt_w     = (const float*)d_in[3];
  const float* dt_b     = (const float*)d_in[4];
  const float* A_log    = (const float*)d_in[5];
  const float* Dp       = (const float*)d_in[6];
  const float* xp_w     = (const float*)d_in[7];
  const float* conv_w   = (const float*)d_in[8];
  const float* conv_b   = (const float*)d_in[9];
  const float* out_w    = (const float*)d_in[10];
  const float* ng       = (const float*)d_in[11];
  const float* nb       = (const float*)d_in[12];
  const float* fw1      = (const float*)d_in[13];
  const float* fb1      = (const float*)d_in[14];
  const float* fw2      = (const float*)d_in[15];
  const float* fb2      = (const float*)d_in[16];
  const float* flg      = (const float*)d_in[17];
  const float* flb      = (const float*)d_in[18];
  const float* alt_embed= (const float*)d_in[19];
  const float* gate_w   = (const float*)d_in[20];
  const float* gate_b   = (const float*)d_in[21];
  float* out = (float*)d_out;

  float* p = (float*)d_ws;
  float* x_buf = p; p += (long)BL * DD;
  float* xdbl  = p; p += 4L * BL * 32;
  float* gateb = p; p += 2L * BB * DD;
  float* aexp  = p; p += (long)NL * NDIR * DIN * NS;
  short* sp = (short*)p;
  short* wbf     = sp; sp += WTOT;
  short* wxp2    = sp; sp += (long)NL * NDIR * NXP2 * 512;
  short* xinb    = sp; sp += 4L * BL * DIN;
  short* zbf     = sp; sp += 4L * BL * DIN;
  short* xcbf    = sp; sp += 4L * BL * DIN;
  short* dtbf    = sp; sp += 4L * BL * DIN;
  short* ybf     = sp; sp += 4L * BL * DIN;
  short* comb_bf = sp; sp += (long)BL * 1024;
  short* hfu_bf  = sp; sp += (long)BL * 512;

  k_transpose<<<2048, 256, 0, stream>>>(feat, x_buf);
  k_gate<<<16, 256, 0, stream>>>(alt_embed, alt_idx, gate_w, gate_b, gateb);
  k_aexp<<<256, 256, 0, stream>>>(A_log, aexp);
  k_wcvt<<<4544, 256, 0, stream>>>(in_w, xp_w, out_w, fw1, fw2, wbf);
  k_wxp<<<8704, 256, 0, stream>>>(xp_w, dt_w, wxp2);

  for (int li = 0; li < NL; li++){
    // xz = perm(x) @ in_w^T  (split epilogue: x_in bf16, z silu bf16)
    k_mgemm<2, 2, 2, false, false, 1><<<dim3(16, 8, 4), 256, 0, stream>>>(
        x_buf, wbf + WOFF_IN + (long)li * NDIR * 1024 * 256, nullptr, xinb, zbf,
        BL, 1024, 256, 0, 1024L * 256, (long)BL * DIN);
    k_conv<<<dim3(8, 2, 32), 256, 0, stream>>>(xinb, conv_w + (long)li * NDIR * DIN * 4,
                                               conv_b + (long)li * NDIR * DIN, xcbf);
    // [B,C | dt] = x_conv @ wxp2^T  (N=544; epilogue: fp32 B,C / softplus bf16 dt)
    k_mgemm<4, 1, 3, false, false, 0><<<dim3(8, 9, 4), 256, 0, stream>>>(
        xcbf, wxp2 + (long)li * NDIR * NXP2 * 512, dt_b + (long)li * NDIR * DIN, xdbl, dtbf,
        BL, NXP2, 512, (long)BL * DIN, (long)NXP2 * 512, 0);
    k_scan<<<dim3(64, 8, 4), 512, 0, stream>>>(xcbf, zbf, dtbf, xdbl,
        aexp + (long)li * NDIR * DIN * NS, Dp + (long)li * NDIR * DIN, ybf);
    // out-proj + residual + LN -> comb_bf (fused)
    k_gemmln<0><<<dim3(32, 1, 4), 256, 0, stream>>>(
        ybf, wbf + WOFF_OUT + (long)li * NDIR * 256 * 512, nullptr, x_buf,
        ng + (long)li * NDIR * DD, nb + (long)li * NDIR * DD, comb_bf,
        (long)BL * DIN, 256L * 512);
    // hfu = gelu(comb @ fw1^T + fb1)  -> bf16
    k_mgemm<2, 2, 1, true, true, 0><<<dim3(16, 4, 1), 256, 0, stream>>>(
        comb_bf, wbf + WOFF_F1 + (long)li * 512 * 1024, fb1 + (long)li * 512, hfu_bf, nullptr,
        BL, 512, 1024, 0, 0, 0);
    // fus2 + bias + LN + gate -> dst (fused)
    float* dst = (li == NL - 1) ? out : x_buf;
    k_gemmln<1><<<dim3(32, 1, 1), 256, 0, stream>>>(
        hfu_bf, wbf + WOFF_F2 + (long)li * 256 * 512, fb2 + (long)li * 256,
        gateb + (long)li * BB * DD, flg + (long)li * DD, flb + (long)li * DD, dst,
        0, 0);
  }
}